// Round 3
// baseline (338.980 us; speedup 1.0000x reference)
//
#include <hip/hip_runtime.h>
#include <hip/hip_bf16.h>

// PIPNet interface scorer: out[p] = W2 . relu(W1 . concat(g1[il[p]], g2[ir[p]]) + b1) + b2
// R3: batch all 16 gather loads in registers before converting (R2's VGPR=52
// proves the compiler serialized load->cvt->ds_write, paying full random-access
// latency 16x per wave). sched_barrier pins the load/pack split.

typedef __bf16 bf16x8 __attribute__((ext_vector_type(8)));
typedef float f32x16 __attribute__((ext_vector_type(16)));

__device__ __forceinline__ unsigned f2bf(float f) {
  union { float f; unsigned u; } v;
  v.f = f;
  unsigned u = v.u;
  // round-to-nearest-even f32 -> bf16
  return (u + 0x7fffu + ((u >> 16) & 1u)) >> 16;
}

// Pre-kernel: W1 [128x128] f32 row-major -> bf16 B-fragments for
// v_mfma_f32_32x32x16_bf16; main-loop load is uniform_base + lane*16.
// Fragment (ks, nt, lane): n = lane&31, h = lane>>5;
//   elements = W1[nt*32+n][ks*16 + h*8 + j], j = 0..7
__global__ __launch_bounds__(256) void w1_frag_kernel(
    const float* __restrict__ W1, uint4* __restrict__ w1f) {
  int t = blockIdx.x * 256 + threadIdx.x;  // 0..2047
  int lane = t & 63;
  int nt = (t >> 6) & 3;
  int ks = t >> 8;
  int n = lane & 31, h = lane >> 5;
  const float4* src =
      (const float4*)(W1 + ((nt * 32 + n) * 128 + ks * 16 + h * 8));
  float4 a = src[0], b = src[1];
  uint4 o;
  o.x = f2bf(a.x) | (f2bf(a.y) << 16);
  o.y = f2bf(a.z) | (f2bf(a.w) << 16);
  o.z = f2bf(b.x) | (f2bf(b.y) << 16);
  o.w = f2bf(b.z) | (f2bf(b.w) << 16);
  w1f[t] = o;
}

#define LDS_STRIDE 136  // shorts; 272B rows, 16B-aligned for ds_read_b128

__global__ __launch_bounds__(256, 4) void pip_main_kernel(
    const float* __restrict__ g1, const float* __restrict__ g2,
    const int* __restrict__ il, const int* __restrict__ ir,
    const bf16x8* __restrict__ w1f,
    const float* __restrict__ b1, const float* __restrict__ w2,
    const float* __restrict__ b2,
    float* __restrict__ out, int P) {
  __shared__ unsigned short A[128 * LDS_STRIDE];  // 34,816 B -> 4 blocks/CU

  const int t = threadIdx.x;
  const int lane = t & 63;
  const int w = t >> 6;
  const int pair0 = blockIdx.x * 128;

  // ---- Cooperative gather: 16 lanes per (pair,side) row of 64 floats ----
  // Round j covers rows r = j*16 + w*4 + g, g = lane>>4. side = g&1 fixed.
  const int sub = lane & 15;          // lane's 16B slice within the row
  const int g = lane >> 4;
  const int side = g & 1;             // 0: left/g1, 1: right/g2
  const int pairB = (w * 4 + g) >> 1; // 0..7
  const float* feat = side ? g2 : g1;
  const int* idxarr = side ? ir : il;

  // Phase 1: all 16 index loads in flight
  int idxv[16];
#pragma unroll
  for (int j = 0; j < 16; ++j) {
    int gp = pair0 + j * 8 + pairB;
    int pidx = (gp < P) ? gp : (P - 1);
    idxv[j] = idxarr[pidx];
  }
  // Phase 2: all 16 row-gather loads in flight (64 VGPRs of payload)
  float4 v[16];
#pragma unroll
  for (int j = 0; j < 16; ++j)
    v[j] = *(const float4*)(feat + (size_t)idxv[j] * 64 + sub * 4);
  __builtin_amdgcn_sched_barrier(0);  // keep pack phase below the loads
  // Phase 3: convert + LDS write
#pragma unroll
  for (int j = 0; j < 16; ++j) {
    unsigned lo = f2bf(v[j].x) | (f2bf(v[j].y) << 16);
    unsigned hi = f2bf(v[j].z) | (f2bf(v[j].w) << 16);
    *(uint2*)(A + (j * 8 + pairB) * LDS_STRIDE + side * 64 + sub * 4) =
        make_uint2(lo, hi);
  }
  __syncthreads();

  // ---- Compute: wave w handles pairs [w*32, w*32+32), full n = 0..127 ----
  const int n = lane & 31;   // MFMA m/n index within tile
  const int h = lane >> 5;   // k-block / row offset half

  f32x16 acc[4];
#pragma unroll
  for (int nt = 0; nt < 4; ++nt)
#pragma unroll
    for (int i = 0; i < 16; ++i) acc[nt][i] = 0.0f;

  const unsigned short* Arow = A + (w * 32 + n) * LDS_STRIDE + h * 8;
#pragma unroll
  for (int ks = 0; ks < 8; ++ks) {
    bf16x8 af = *(const bf16x8*)(Arow + ks * 16);
#pragma unroll
    for (int nt = 0; nt < 4; ++nt) {
      bf16x8 bfr = w1f[(ks * 4 + nt) * 64 + lane];
      acc[nt] = __builtin_amdgcn_mfma_f32_32x32x16_bf16(af, bfr, acc[nt], 0, 0, 0);
    }
  }

  // ---- Epilogue: out[p] = sum_n relu(acc + b1[n]) * w2[n] + b2 ----
  // C/D layout: col(n) = lane&31 (+32*nt), row(m) = (r&3) + 8*(r>>2) + 4*h.
  float b1v[4], w2v[4];
#pragma unroll
  for (int nt = 0; nt < 4; ++nt) {
    b1v[nt] = b1[nt * 32 + n];
    w2v[nt] = w2[nt * 32 + n];
  }
  const float bias2 = b2[0];

#pragma unroll
  for (int r = 0; r < 16; ++r) {
    float s = 0.0f;
#pragma unroll
    for (int nt = 0; nt < 4; ++nt) {
      float vv = acc[nt][r] + b1v[nt];
      vv = fmaxf(vv, 0.0f);
      s = fmaf(vv, w2v[nt], s);
    }
    s += __shfl_xor(s, 1);
    s += __shfl_xor(s, 2);
    s += __shfl_xor(s, 4);
    s += __shfl_xor(s, 8);
    s += __shfl_xor(s, 16);
    if (n == 0) {
      int row = (r & 3) + 8 * (r >> 2) + 4 * h;
      int gp = pair0 + w * 32 + row;
      if (gp < P) out[gp] = s + bias2;
    }
  }
}

extern "C" void kernel_launch(void* const* d_in, const int* in_sizes, int n_in,
                              void* d_out, int out_size, void* d_ws, size_t ws_size,
                              hipStream_t stream) {
  const float* g1 = (const float*)d_in[0];   // graph1_x [N,64] f32
  const float* g2 = (const float*)d_in[1];   // graph2_x [N,64] f32
  const int* il = (const int*)d_in[2];       // idx_left [P] int32
  const int* ir = (const int*)d_in[3];       // idx_right [P] int32
  const float* W1 = (const float*)d_in[4];   // [128,128]
  const float* b1 = (const float*)d_in[5];   // [128]
  const float* w2 = (const float*)d_in[6];   // [1,128]
  const float* b2 = (const float*)d_in[7];   // [1]
  float* out = (float*)d_out;                // [P,1] f32
  const int P = out_size;

  // d_ws: 32 KB of bf16 W1 B-fragments (rebuilt every call; ws is re-poisoned)
  w1_frag_kernel<<<8, 256, 0, stream>>>(W1, (uint4*)d_ws);

  const int nblocks = (P + 127) / 128;
  pip_main_kernel<<<nblocks, 256, 0, stream>>>(
      g1, g2, il, ir, (const bf16x8*)d_ws, b1, w2, b2, out, P);
}